// Round 12
// baseline (54.677 us; speedup 1.0000x reference)
//
#include <hip/hip_runtime.h>

// B=4, T=2048, D=1024, P=128
#define BB 4
#define TT 2048
#define DD 1024
#define PP 128
#define NC 16
#define CH 128

typedef __attribute__((ext_vector_type(8))) short bf16x8;
typedef __attribute__((ext_vector_type(4))) float f32x4;

__device__ inline ushort f2bf(float f) {
  unsigned u = __builtin_bit_cast(unsigned, f);
  u = (u + 0x7FFF + ((u >> 16) & 1)) >> 16;  // RNE
  return (ushort)u;
}

__device__ inline void gll16(const void* g, void* l) {
  __builtin_amdgcn_global_load_lds(
      (const __attribute__((address_space(1))) void*)g,
      (__attribute__((address_space(3))) void*)l, 16, 0, 0);
}

// T2 swizzles: kbyte bits 4.. ^= low row bits. 256B / 128B / 64B rows.
__device__ inline int swzoff(int row, int kbyte) {
  return row * 256 + (kbyte ^ ((row & 7) << 4));
}
__device__ inline int swz128(int row, int kbyte) {
  return row * 128 + (kbyte ^ ((row & 7) << 4));
}
__device__ inline int swz64(int row, int kbyte) {
  return row * 64 + (kbyte ^ ((row & 3) << 4));
}

template <int NI, int NT>
__device__ inline void stage_swz(const ushort* __restrict__ g, int ld, int koff,
                                 char* lds, int tid) {
#pragma unroll
  for (int j = 0; j < NI; ++j) {
    int L = j * (NT * 16) + tid * 16;
    int row = L >> 8;
    int off = (L & 255) ^ ((row & 7) << 4);
    gll16(g + (size_t)row * ld + koff + (off >> 1),
          lds + j * (NT * 16) + ((tid & (NT - 64)) << 4));
  }
}
template <int NI, int NT>
__device__ inline void stage_swz128(const ushort* __restrict__ g, int ld,
                                    int koff, char* lds, int tid) {
#pragma unroll
  for (int j = 0; j < NI; ++j) {
    int L = j * (NT * 16) + tid * 16;
    int row = L >> 7;
    int off = (L & 127) ^ ((row & 7) << 4);
    gll16(g + (size_t)row * ld + koff + (off >> 1),
          lds + j * (NT * 16) + ((tid & (NT - 64)) << 4));
  }
}

__device__ inline bf16x8 ld_swz(const char* lds, int row, int kbyte) {
  return *(const bf16x8*)(lds + swzoff(row, kbyte));
}
__device__ inline bf16x8 ld_swz128(const char* lds, int row, int kbyte) {
  return *(const bf16x8*)(lds + swz128(row, kbyte));
}

// ---------------------------------------------------------------------------
// Tiled transpose-convert weight prep: coalesced reads AND writes via LDS.
// ---------------------------------------------------------------------------
__global__ __launch_bounds__(256) void prep_t(
    const float* __restrict__ Qf, const float* __restrict__ Kf,
    const float* __restrict__ W_in, const float* __restrict__ b_in,
    const float* __restrict__ W_v, const float* __restrict__ b_v,
    const float* __restrict__ W_o, ushort* __restrict__ WcatT,
    ushort* __restrict__ QKcT, ushort* __restrict__ WoT,
    float* __restrict__ bcat) {
  const int bid = blockIdx.x;
  const int t = threadIdx.x;
  if (bid == 104) {
    bcat[t] = (t < 128) ? b_in[t] : b_v[t - 128];
    return;
  }
  const float* src;
  ushort* dst;
  int ld_src, ld_dst, nn0;
  if (bid < 64) {                  // WcatT[256][1024] from W_in/W_v [1024][128]
    int tn = bid >> 4, tk = bid & 15;
    src = (tn < 2) ? W_in : W_v;
    nn0 = (tn & 1) * 64;
    ld_src = 128;
    src += (size_t)(tk * 64) * 128;
    dst = WcatT + (size_t)(tn * 64) * 1024 + tk * 64;
    ld_dst = 1024;
  } else if (bid < 96) {           // WoT[1024][128] from W_o [128][1024]
    int j = bid - 64, tn = j >> 1, tk = j & 1;
    src = W_o;
    nn0 = tn * 64;
    ld_src = 1024;
    src += (size_t)(tk * 64) * 1024;
    dst = WoT + (size_t)(tn * 64) * 128 + tk * 64;
    ld_dst = 128;
  } else {                         // QKcT[256][128] from Qf/Kf [128][128]
    int j = bid - 96, tn = j >> 1, tk = j & 1;
    src = (tn < 2) ? Qf : Kf;
    nn0 = (tn & 1) * 64;
    ld_src = 128;
    src += (size_t)(tk * 64) * 128;
    dst = QKcT + (size_t)(tn * 64) * 128 + tk * 64;
    ld_dst = 128;
  }
  __shared__ ushort Tt[64][68];
  const int kr = t >> 4, nc = (t & 15) * 4;
#pragma unroll
  for (int p = 0; p < 4; ++p) {
    float4 v = *(const float4*)&src[(size_t)(p * 16 + kr) * ld_src + nn0 + nc];
    Tt[p * 16 + kr][nc + 0] = f2bf(v.x);
    Tt[p * 16 + kr][nc + 1] = f2bf(v.y);
    Tt[p * 16 + kr][nc + 2] = f2bf(v.z);
    Tt[p * 16 + kr][nc + 3] = f2bf(v.w);
  }
  __syncthreads();
  const int nr = t >> 4, kc = (t & 15) * 4;
#pragma unroll
  for (int p = 0; p < 4; ++p) {
    ushort4 o;
    o.x = Tt[kc + 0][p * 16 + nr];
    o.y = Tt[kc + 1][p * 16 + nr];
    o.z = Tt[kc + 2][p * 16 + nr];
    o.w = Tt[kc + 3][p * 16 + nr];
    *(ushort4*)&dst[(size_t)(p * 16 + nr) * ld_dst + kc] = o;
  }
}

// ---------------------------------------------------------------------------
// GEMM1 (fused x-convert + QK projection), tile 32x256, BK=64, 512 thr.
// grid 256 row-blocks: each x strip read ONCE (no bn split).
// Main loop: dbuf [A 4K | B 32K] x2, counted vmcnt(4).
// Epilogue per block (32 rows, all 256 cols):
//   cols 0-127  -> XP tile -> swizzled LDS
//   cols 128-255-> V global + VTt LDS transpose -> VT
//   stage QKcT 64KB; QK GEMM (M=32,N=256,K=128); Q -> Qb;
//   Kd=(K*decay) -> swz64 LDS -> KdT coalesced.
// ---------------------------------------------------------------------------
__global__ __launch_bounds__(512) void gemm_xw(
    const float* __restrict__ x, const ushort* __restrict__ WcatT,
    const ushort* __restrict__ QKcT, const float* __restrict__ bcat,
    const float* __restrict__ decay, ushort* __restrict__ Qb,
    ushort* __restrict__ KdT, ushort* __restrict__ V,
    ushort* __restrict__ VT) {
  __shared__ char sm[84992];  // main 72K dbuf; epi: XP 8K | QKcT 64K | VTt 10K
  const int bm = blockIdx.x * 32;
  const int tid = threadIdx.x, w = tid >> 6, l = tid & 63;
  const int lr = l & 15, lk = l >> 4;

  const int arow = tid >> 4;        // 32 rows, 16 thr/row
  const int acol = (tid & 15) * 4;  // 4 floats/thread
  const float* Ax = x + (size_t)(bm + arow) * DD + acol;

  float4 ra;
  f32x4 z = {0.f, 0.f, 0.f, 0.f};
  f32x4 acc[2][2];
#pragma unroll
  for (int m = 0; m < 2; ++m)
#pragma unroll
    for (int n = 0; n < 2; ++n) acc[m][n] = z;

#define LOADA(t) { ra = *(const float4*)(Ax + (((t) & 15) << 6)); }
#define WRITEA(lds)                                              \
  {                                                              \
    ushort4 pk;                                                  \
    pk.x = f2bf(ra.x); pk.y = f2bf(ra.y);                        \
    pk.z = f2bf(ra.z); pk.w = f2bf(ra.w);                        \
    *(ushort4*)((lds) + swz128(arow, acol * 2)) = pk;            \
  }

  LOADA(0);
  stage_swz128<4, 512>(WcatT, DD, 0, sm + 4096, tid);
  asm volatile("s_waitcnt vmcnt(4)" ::: "memory");  // A(0) reg ready
  WRITEA(sm);
  LOADA(1);

  int cur = 0;
  for (int t = 0; t < 16; ++t) {
    char* nxt = sm + (cur ^ 1) * 36864;
    stage_swz128<4, 512>(WcatT, DD, ((t + 1) & 15) << 6, nxt + 4096, tid);
    asm volatile("s_waitcnt vmcnt(4)" ::: "memory");  // B(t)+A(t+1) done
    WRITEA(nxt);
    LOADA(t + 2);  // wrapped, harmless
    asm volatile("s_waitcnt lgkmcnt(0)" ::: "memory");
    __builtin_amdgcn_s_barrier();
    const char* cp = sm + cur * 36864;
#pragma unroll
    for (int ks = 0; ks < 2; ++ks) {
      const int kb = ks * 64 + lk * 16;
      bf16x8 af[2], bfp[2];
#pragma unroll
      for (int m = 0; m < 2; ++m)
        af[m] = ld_swz128(cp, m * 16 + lr, kb);
#pragma unroll
      for (int n = 0; n < 2; ++n)
        bfp[n] = ld_swz128(cp + 4096, w * 32 + n * 16 + lr, kb);
#pragma unroll
      for (int m = 0; m < 2; ++m)
#pragma unroll
        for (int n = 0; n < 2; ++n)
          acc[m][n] = __builtin_amdgcn_mfma_f32_16x16x32_bf16(af[m], bfp[n], acc[m][n], 0, 0, 0);
    }
    __builtin_amdgcn_s_barrier();
    cur ^= 1;
  }
  asm volatile("s_waitcnt vmcnt(0)" ::: "memory");
  __syncthreads();  // all waves' wrapped gll16 landed; LDS reusable
#undef LOADA
#undef WRITEA

  // ---- (a) XP -> LDS[0,8K) (waves 0-3); V global + VTt (waves 4-7) ----
  ushort(*VTt)[40] = (ushort(*)[40]) & sm[73728];  // 128 x 40 ushort
#pragma unroll
  for (int m = 0; m < 2; ++m)
#pragma unroll
    for (int n = 0; n < 2; ++n) {
      const int rowl = m * 16 + lk * 4;        // local time 0..31
      const int col = w * 32 + n * 16 + lr;    // 0..255 (wave-uniform half)
      const float bv = bcat[col];
      if (col < 128) {
#pragma unroll
        for (int j = 0; j < 4; ++j)
          *(ushort*)(sm + swzoff(rowl + j, col * 2)) = f2bf(acc[m][n][j] + bv);
      } else {
        const int cc = col - 128;
#pragma unroll
        for (int j = 0; j < 4; ++j) {
          ushort u = f2bf(acc[m][n][j] + bv);
          V[(size_t)(bm + rowl + j) * PP + cc] = u;
          VTt[cc][rowl + j] = u;
        }
      }
    }
  // ---- (b) stage QKcT[256][128] (64 KB, L2-hot) at sm+8K ----
  stage_swz<8, 512>(QKcT, PP, 0, sm + 8192, tid);
  __syncthreads();  // drains lgkm (XP/VTt) + vm (stage)

  // ---- (c) VT dump: 128 feats x 32 times, coalesced 16B/lane ----
  {
    const int cc = tid >> 2, ch = tid & 3;
    bf16x8 v = *(const bf16x8*)&VTt[cc][ch * 8];
    *(bf16x8*)&VT[(size_t)cc * (BB * TT) + bm + ch * 8] = v;
  }

  // ---- (d) QK GEMM: M=32, N=256, K=128 ----
  f32x4 aq[2][2];
#pragma unroll
  for (int m = 0; m < 2; ++m)
#pragma unroll
    for (int n = 0; n < 2; ++n) aq[m][n] = z;
#pragma unroll
  for (int ks = 0; ks < 4; ++ks) {
    const int kb = ks * 64 + lk * 16;
    bf16x8 af[2], bfp[2];
#pragma unroll
    for (int m = 0; m < 2; ++m)
      af[m] = ld_swz(sm, m * 16 + lr, kb);
#pragma unroll
    for (int n = 0; n < 2; ++n)
      bfp[n] = ld_swz(sm + 8192, w * 32 + n * 16 + lr, kb);
#pragma unroll
    for (int m = 0; m < 2; ++m)
#pragma unroll
      for (int n = 0; n < 2; ++n)
        aq[m][n] = __builtin_amdgcn_mfma_f32_16x16x32_bf16(af[m], bfp[n], aq[m][n], 0, 0, 0);
  }
  __syncthreads();  // XP reads done; sm[0,8K) reusable for Kd tile

  // ---- (e) Q -> Qb (waves 0-3); Kd=(K*decay) -> swz64 LDS (waves 4-7) ----
#pragma unroll
  for (int m = 0; m < 2; ++m)
#pragma unroll
    for (int n = 0; n < 2; ++n) {
      const int rowl = m * 16 + lk * 4;
      const int col = w * 32 + n * 16 + lr;
      if (col < 128) {
#pragma unroll
        for (int j = 0; j < 4; ++j)
          Qb[(size_t)(bm + rowl + j) * PP + col] = f2bf(aq[m][n][j]);
      } else {
        const int cc = col - 128;
#pragma unroll
        for (int j = 0; j < 4; ++j) {
          float v = aq[m][n][j] * decay[(bm + rowl + j) & (TT - 1)];
          *(ushort*)(sm + swz64(cc, (rowl + j) * 2)) = f2bf(v);
        }
      }
    }
  __syncthreads();  // Kd tile complete

  // ---- (f) KdT dump: 128 feats x 32 times, coalesced 16B/lane ----
  {
    const int cc = tid >> 2, ch = tid & 3;
    bf16x8 v = *(const bf16x8*)(sm + swz64(cc, ch * 16));
    *(bf16x8*)&KdT[(size_t)cc * (BB * TT) + bm + ch * 8] = v;
  }
}

// ---------------------------------------------------------------------------
// Chunk state S[bc][j][i] = sum_s Kd[s][j]*V[s][i], global-direct MFMA.
// grid 256: (chunk, quadrant qj x qi), XCD swizzle co-locates a chunk's 4.
// ---------------------------------------------------------------------------
__global__ __launch_bounds__(256) void chunk_state(
    const ushort* __restrict__ KdT, const ushort* __restrict__ VT,
    float* __restrict__ Sc) {
  const int p = blockIdx.x;
  const int xcd = p & 7, idx = p >> 3;
  const int bc = xcd + 8 * (idx >> 2);  // 0..63
  const int q = idx & 3;
  const int qj = q >> 1, qi = q & 1;
  const size_t r0 = (size_t)(bc >> 4) * TT + (bc & 15) * CH;
  const int tid = threadIdx.x, w = tid >> 6, l = tid & 63;
  const int wr = w >> 1, wc = w & 1, lr = l & 15, lk = l >> 4;

  f32x4 z = {0.f, 0.f, 0.f, 0.f};
  f32x4 acc[2][2];
#pragma unroll
  for (int m = 0; m < 2; ++m)
#pragma unroll
    for (int n = 0; n < 2; ++n) acc[m][n] = z;
#pragma unroll
  for (int ks = 0; ks < 4; ++ks) {
    const int kk = ks * 32 + lk * 8;
    bf16x8 af[2], bf[2];
#pragma unroll
    for (int m = 0; m < 2; ++m)
      af[m] = *(const bf16x8*)&KdT[(size_t)(qj * 64 + wr * 32 + m * 16 + lr) * (BB * TT) + r0 + kk];
#pragma unroll
    for (int n = 0; n < 2; ++n)
      bf[n] = *(const bf16x8*)&VT[(size_t)(qi * 64 + wc * 32 + n * 16 + lr) * (BB * TT) + r0 + kk];
#pragma unroll
    for (int m = 0; m < 2; ++m)
#pragma unroll
      for (int n = 0; n < 2; ++n)
        acc[m][n] = __builtin_amdgcn_mfma_f32_16x16x32_bf16(af[m], bf[n], acc[m][n], 0, 0, 0);
  }
#pragma unroll
  for (int m = 0; m < 2; ++m)
#pragma unroll
    for (int n = 0; n < 2; ++n)
#pragma unroll
      for (int j = 0; j < 4; ++j)
        Sc[(size_t)bc * 16384 +
           (size_t)(qj * 64 + wr * 32 + m * 16 + lk * 4 + j) * 128 +
           (qi * 64 + wc * 32 + n * 16 + lr)] = acc[m][n][j];
}

// ---------------------------------------------------------------------------
// Exclusive prefix over chunks -> SxT bf16
// ---------------------------------------------------------------------------
__global__ __launch_bounds__(256) void chunk_scan(const float* __restrict__ Sc,
                                                  ushort* __restrict__ SxT) {
  const int b = blockIdx.y;
  const int e = blockIdx.x * 256 + threadIdx.x;
  float run = 0.f;
#pragma unroll
  for (int c = 0; c < NC; ++c) {
    const size_t idx = (size_t)(b * NC + c) * 16384 + e;
    SxT[idx] = f2bf(run);
    run += Sc[idx];
  }
}

// ---------------------------------------------------------------------------
// Attention core, 4 blocks per (b,c): (hr, hc). grid 256, XCD co-located.
// Y = tril(Q V^T) Kd + Q Sx   (decay folded into Kd and Sx)
// ---------------------------------------------------------------------------
__global__ __launch_bounds__(256) void attn_mfma(
    const ushort* __restrict__ Qb, const ushort* __restrict__ V,
    const ushort* __restrict__ KdT, const ushort* __restrict__ SxT,
    ushort* __restrict__ Y) {
  __shared__ char Am[64 * 256];  // 16 KB swizzled scores, local rows
  const int p = blockIdx.x;
  const int xcd = p & 7, idx = p >> 3;
  const int bc = xcd + 8 * (idx >> 2);
  const int q = idx & 3;
  const int hr = q >> 1, hc = q & 1;
  const size_t r0 = (size_t)(bc >> 4) * TT + (bc & 15) * CH;
  const int tid = threadIdx.x, w = tid >> 6, l = tid & 63;
  const int wr = w >> 1, wc = w & 1, lr = l & 15, lk = l >> 4;

  f32x4 z = {0.f, 0.f, 0.f, 0.f};
  f32x4 a1[2][4];
#pragma unroll
  for (int m = 0; m < 2; ++m)
#pragma unroll
    for (int n = 0; n < 4; ++n) a1[m][n] = z;

  // phase 1: raw scores A[t][s] = Q[t]·V[s], rows hr*64 + wr*32 + m*16
#pragma unroll
  for (int ks = 0; ks < 4; ++ks) {
    const int kk = ks * 32 + lk * 8;
    bf16x8 af[2], bf[4];
#pragma unroll
    for (int m = 0; m < 2; ++m)
      af[m] = *(const bf16x8*)&Qb[(r0 + hr * 64 + wr * 32 + m * 16 + lr) * 128 + kk];
#pragma unroll
    for (int n = 0; n < 4; ++n)
      bf[n] = *(const bf16x8*)&V[(r0 + wc * 64 + n * 16 + lr) * 128 + kk];
#pragma unroll
    for (int m = 0; m < 2; ++m)
#pragma unroll
      for (int n = 0; n < 4; ++n)
        a1[m][n] = __builtin_amdgcn_mfma_f32_16x16x32_bf16(af[m], bf[n], a1[m][n], 0, 0, 0);
  }
#pragma unroll
  for (int m = 0; m < 2; ++m)
#pragma unroll
    for (int n = 0; n < 4; ++n)
#pragma unroll
      for (int j = 0; j < 4; ++j) {
        int tl = wr * 32 + m * 16 + lk * 4 + j;  // local row
        int t = hr * 64 + tl;
        int s = wc * 64 + n * 16 + lr;
        float v = (s <= t) ? a1[m][n][j] : 0.f;
        *(ushort*)(Am + swzoff(tl, s * 2)) = f2bf(v);
      }
  __syncthreads();

  // phase 2: Y[64x64] = Am @ Kd + Q @ Sx ; warp grid 2x2, wave 32x32
  f32x4 a2[2][2];
#pragma unroll
  for (int m = 0; m < 2; ++m)
#pragma unroll
    for (int n = 0; n < 2; ++n) a2[m][n] = z;
#pragma unroll
  for (int ks = 0; ks < 4; ++ks) {
    const int kb = ks * 64 + lk * 16, kk = ks * 32 + lk * 8;
    bf16x8 af[2], bf[2];
#pragma unroll
    for (int m = 0; m < 2; ++m)
      af[m] = ld_swz(Am, wr * 32 + m * 16 + lr, kb);
#pragma unroll
    for (int n = 0; n < 2; ++n)
      bf[n] = *(const bf16x8*)&KdT[(size_t)(hc * 64 + wc * 32 + n * 16 + lr) * (BB * TT) + r0 + kk];
#pragma unroll
    for (int m = 0; m < 2; ++m)
#pragma unroll
      for (int n = 0; n < 2; ++n)
        a2[m][n] = __builtin_amdgcn_mfma_f32_16x16x32_bf16(af[m], bf[n], a2[m][n], 0, 0, 0);
  }
#pragma unroll
  for (int ks = 0; ks < 4; ++ks) {
    const int kk = ks * 32 + lk * 8;
    bf16x8 af[2], bf[2];
#pragma unroll
    for (int m = 0; m < 2; ++m)
      af[m] = *(const bf16x8*)&Qb[(r0 + hr * 64 + wr * 32 + m * 16 + lr) * 128 + kk];
#pragma unroll
    for (int n = 0; n < 2; ++n)
      bf[n] = *(const bf16x8*)&SxT[(size_t)bc * 16384 +
                                   (size_t)(hc * 64 + wc * 32 + n * 16 + lr) * 128 + kk];
#pragma unroll
    for (int m = 0; m < 2; ++m)
#pragma unroll
      for (int n = 0; n < 2; ++n)
        a2[m][n] = __builtin_amdgcn_mfma_f32_16x16x32_bf16(af[m], bf[n], a2[m][n], 0, 0, 0);
  }
#pragma unroll
  for (int m = 0; m < 2; ++m)
#pragma unroll
    for (int n = 0; n < 2; ++n)
#pragma unroll
      for (int j = 0; j < 4; ++j) {
        int t = hr * 64 + wr * 32 + m * 16 + lk * 4 + j;
        int col = hc * 64 + wc * 32 + n * 16 + lr;
        Y[(r0 + t) * 128 + col] = f2bf(a2[m][n][j]);
      }
}

// ---------------------------------------------------------------------------
// GEMM3: Y[8192x128] @ W_o + b_o -> out fp32. Single-shot K=128. grid 1024.
// ---------------------------------------------------------------------------
__global__ __launch_bounds__(256) void gemm_out(
    const ushort* __restrict__ Y, const ushort* __restrict__ WoT,
    const float* __restrict__ b_o, float* __restrict__ out) {
  __shared__ char sm[49152];  // A 16K | B 32K
  const int bid = blockIdx.x;
  const int swz = (bid & 7) * 128 + (bid >> 3);
  const int bm = (swz >> 3) * 64, bn = (swz & 7) * 128;
  const int tid = threadIdx.x, w = tid >> 6, l = tid & 63;
  const int wr = w >> 1, wc = w & 1, lr = l & 15, lk = l >> 4;
  stage_swz<4, 256>(Y + (size_t)bm * PP, PP, 0, sm, tid);
  stage_swz<8, 256>(WoT + (size_t)bn * PP, PP, 0, sm + 16384, tid);
  f32x4 z = {0.f, 0.f, 0.f, 0.f};
  f32x4 acc[2][4];
#pragma unroll
  for (int m = 0; m < 2; ++m)
#pragma unroll
    for (int n = 0; n < 4; ++n) acc[m][n] = z;
  __syncthreads();
#pragma unroll
  for (int ks = 0; ks < 4; ++ks) {
    const int kb = ks * 64 + lk * 16;
    bf16x8 af[2], bfp[4];
#pragma unroll
    for (int m = 0; m < 2; ++m) af[m] = ld_swz(sm, wr * 32 + m * 16 + lr, kb);
#pragma unroll
    for (int n = 0; n < 4; ++n)
      bfp[n] = ld_swz(sm + 16384, wc * 64 + n * 16 + lr, kb);
#pragma unroll
    for (int m = 0; m < 2; ++m)
#pragma unroll
      for (int n = 0; n < 4; ++n)
        acc[m][n] = __builtin_amdgcn_mfma_f32_16x16x32_bf16(af[m], bfp[n], acc[m][n], 0, 0, 0);
  }
#pragma unroll
  for (int m = 0; m < 2; ++m)
#pragma unroll
    for (int n = 0; n < 4; ++n) {
      const int rowb = bm + wr * 32 + m * 16 + lk * 4;
      const int col = bn + wc * 64 + n * 16 + lr;
      const float bv = b_o[col];
#pragma unroll
      for (int j = 0; j < 4; ++j)
        out[(size_t)(rowb + j) * DD + col] = acc[m][n][j] + bv;
    }
}

// ---------------------------------------------------------------------------
extern "C" void kernel_launch(void* const* d_in, const int* in_sizes, int n_in,
                              void* d_out, int out_size, void* d_ws, size_t ws_size,
                              hipStream_t stream) {
  const float* x = (const float*)d_in[0];
  const float* Qf = (const float*)d_in[1];
  const float* Kf = (const float*)d_in[2];
  const float* W_in = (const float*)d_in[3];
  const float* b_in = (const float*)d_in[4];
  const float* W_v = (const float*)d_in[5];
  const float* b_v = (const float*)d_in[6];
  const float* W_o = (const float*)d_in[7];
  const float* b_o = (const float*)d_in[8];
  const float* decay = (const float*)d_in[9];
  float* out = (float*)d_out;
  char* W = (char*)d_ws;

  ushort* V     = (ushort*)(W);                  // 2 MB
  ushort* VT    = (ushort*)(W + 2097152);        // 2 MB
  ushort* Qb    = (ushort*)(W + 4194304);        // 2 MB
  ushort* KdT   = (ushort*)(W + 6291456);        // 2 MB
  float*  Sc    = (float*)(W + 8388608);         // 4 MB
  ushort* SxT   = (ushort*)(W + 12582912);       // 2 MB
  ushort* Yb    = (ushort*)(W + 14680064);       // 2 MB
  ushort* WcatT = (ushort*)(W + 16777216);       // 512 KB
  ushort* QKcT  = (ushort*)(W + 17301504);       // 64 KB
  ushort* WoT   = (ushort*)(W + 17367040);       // 256 KB
  float*  bcat  = (float*)(W + 17629184);        // 1 KB

  prep_t<<<105, 256, 0, stream>>>(Qf, Kf, W_in, b_in, W_v, b_v, W_o,
                                  WcatT, QKcT, WoT, bcat);
  gemm_xw<<<256, 512, 0, stream>>>(x, WcatT, QKcT, bcat, decay,
                                   Qb, KdT, V, VT);
  chunk_state<<<256, 256, 0, stream>>>(KdT, VT, Sc);
  chunk_scan<<<dim3(64, BB), 256, 0, stream>>>(Sc, SxT);
  attn_mfma<<<256, 256, 0, stream>>>(Qb, V, KdT, SxT, Yb);
  gemm_out<<<1024, 256, 0, stream>>>(Yb, WoT, b_o, out);
}

// Round 13
// 47.862 us; speedup vs baseline: 1.1424x; 1.1424x over previous
//
#include <hip/hip_runtime.h>

// B=4, T=2048, D=1024, P=128
#define BB 4
#define TT 2048
#define DD 1024
#define PP 128
#define NC 16
#define CH 128

typedef __attribute__((ext_vector_type(8))) short bf16x8;
typedef __attribute__((ext_vector_type(4))) float f32x4;

__device__ inline ushort f2bf(float f) {
  unsigned u = __builtin_bit_cast(unsigned, f);
  u = (u + 0x7FFF + ((u >> 16) & 1)) >> 16;  // RNE
  return (ushort)u;
}
__device__ inline float bf2f(ushort u) {
  unsigned v = ((unsigned)u) << 16;
  return __builtin_bit_cast(float, v);
}

__device__ inline void gll16(const void* g, void* l) {
  __builtin_amdgcn_global_load_lds(
      (const __attribute__((address_space(1))) void*)g,
      (__attribute__((address_space(3))) void*)l, 16, 0, 0);
}

// T2 swizzle, 256B rows (128 bf16): kbyte bits 4..6 ^= row&7.
__device__ inline int swzoff(int row, int kbyte) {
  return row * 256 + (kbyte ^ ((row & 7) << 4));
}
// T2 swizzle, 128B rows (64 bf16)
__device__ inline int swz128(int row, int kbyte) {
  return row * 128 + (kbyte ^ ((row & 7) << 4));
}

template <int NI, int NT>
__device__ inline void stage_swz(const ushort* __restrict__ g, int ld, int koff,
                                 char* lds, int tid) {
#pragma unroll
  for (int j = 0; j < NI; ++j) {
    int L = j * (NT * 16) + tid * 16;
    int row = L >> 8;
    int off = (L & 255) ^ ((row & 7) << 4);
    gll16(g + (size_t)row * ld + koff + (off >> 1),
          lds + j * (NT * 16) + ((tid & (NT - 64)) << 4));
  }
}
template <int NI, int NT>
__device__ inline void stage_swz128(const ushort* __restrict__ g, int ld,
                                    int koff, char* lds, int tid) {
#pragma unroll
  for (int j = 0; j < NI; ++j) {
    int L = j * (NT * 16) + tid * 16;
    int row = L >> 7;
    int off = (L & 127) ^ ((row & 7) << 4);
    gll16(g + (size_t)row * ld + koff + (off >> 1),
          lds + j * (NT * 16) + ((tid & (NT - 64)) << 4));
  }
}

__device__ inline bf16x8 ld_swz(const char* lds, int row, int kbyte) {
  return *(const bf16x8*)(lds + swzoff(row, kbyte));
}
__device__ inline bf16x8 ld_swz128(const char* lds, int row, int kbyte) {
  return *(const bf16x8*)(lds + swz128(row, kbyte));
}

__device__ inline bf16x8 pack8(const float4& a, const float4& b) {
  bf16x8 v;
  v[0] = (short)f2bf(a.x); v[1] = (short)f2bf(a.y);
  v[2] = (short)f2bf(a.z); v[3] = (short)f2bf(a.w);
  v[4] = (short)f2bf(b.x); v[5] = (short)f2bf(b.y);
  v[6] = (short)f2bf(b.z); v[7] = (short)f2bf(b.w);
  return v;
}

// ---------------------------------------------------------------------------
// Tiled transpose-convert weight prep: coalesced reads AND writes via LDS.
// ---------------------------------------------------------------------------
__global__ __launch_bounds__(256) void prep_t(
    const float* __restrict__ Qf, const float* __restrict__ Kf,
    const float* __restrict__ W_in, const float* __restrict__ b_in,
    const float* __restrict__ W_v, const float* __restrict__ b_v,
    const float* __restrict__ W_o, ushort* __restrict__ WcatT,
    ushort* __restrict__ QKcT, ushort* __restrict__ WoT,
    float* __restrict__ bcat) {
  const int bid = blockIdx.x;
  const int t = threadIdx.x;
  if (bid == 104) {
    bcat[t] = (t < 128) ? b_in[t] : b_v[t - 128];
    return;
  }
  const float* src;
  ushort* dst;
  int ld_src, ld_dst, nn0;
  if (bid < 64) {                  // WcatT[256][1024] from W_in/W_v [1024][128]
    int tn = bid >> 4, tk = bid & 15;
    src = (tn < 2) ? W_in : W_v;
    nn0 = (tn & 1) * 64;
    ld_src = 128;
    src += (size_t)(tk * 64) * 128;
    dst = WcatT + (size_t)(tn * 64) * 1024 + tk * 64;
    ld_dst = 1024;
  } else if (bid < 96) {           // WoT[1024][128] from W_o [128][1024]
    int j = bid - 64, tn = j >> 1, tk = j & 1;
    src = W_o;
    nn0 = tn * 64;
    ld_src = 1024;
    src += (size_t)(tk * 64) * 1024;
    dst = WoT + (size_t)(tn * 64) * 128 + tk * 64;
    ld_dst = 128;
  } else {                         // QKcT[256][128] from Qf/Kf [128][128]
    int j = bid - 96, tn = j >> 1, tk = j & 1;
    src = (tn < 2) ? Qf : Kf;
    nn0 = (tn & 1) * 64;
    ld_src = 128;
    src += (size_t)(tk * 64) * 128;
    dst = QKcT + (size_t)(tn * 64) * 128 + tk * 64;
    ld_dst = 128;
  }
  __shared__ ushort Tt[64][68];
  const int kr = t >> 4, nc = (t & 15) * 4;
#pragma unroll
  for (int p = 0; p < 4; ++p) {
    float4 v = *(const float4*)&src[(size_t)(p * 16 + kr) * ld_src + nn0 + nc];
    Tt[p * 16 + kr][nc + 0] = f2bf(v.x);
    Tt[p * 16 + kr][nc + 1] = f2bf(v.y);
    Tt[p * 16 + kr][nc + 2] = f2bf(v.z);
    Tt[p * 16 + kr][nc + 3] = f2bf(v.w);
  }
  __syncthreads();
  const int nr = t >> 4, kc = (t & 15) * 4;
#pragma unroll
  for (int p = 0; p < 4; ++p) {
    ushort4 o;
    o.x = Tt[kc + 0][p * 16 + nr];
    o.y = Tt[kc + 1][p * 16 + nr];
    o.z = Tt[kc + 2][p * 16 + nr];
    o.w = Tt[kc + 3][p * 16 + nr];
    *(ushort4*)&dst[(size_t)(p * 16 + nr) * ld_dst + kc] = o;
  }
}

// ---------------------------------------------------------------------------
// GEMM1 (fused x-convert + QK projection):
//  main loop: x fp32 [8192x1024] @ WcatT, BM=64 BN=128 BK=64, dbuf vmcnt(2).
//  bn==0 epilogue: XP->LDS; stage QKcT 64KB; QK GEMM; Q->Qb; Kd->KdT.
//  bn==1 epilogue: V + VT (LDS transpose). XP never touches global.
// ---------------------------------------------------------------------------
__global__ __launch_bounds__(512) void gemm_xw(
    const float* __restrict__ x, const ushort* __restrict__ WcatT,
    const ushort* __restrict__ QKcT, const float* __restrict__ bcat,
    const float* __restrict__ decay, ushort* __restrict__ Qb,
    ushort* __restrict__ KdT, ushort* __restrict__ V,
    ushort* __restrict__ VT) {
  __shared__ char sm[81920];  // main loop: 2 x [A 8K | B 16K]; QK: [XP 16K | B 64K]
  const int bid = blockIdx.x;
  const int swz = (bid & 7) * 32 + (bid >> 3);
  const int bm = (swz >> 1) * 64;
  const int bn = (swz & 1) * 128;
  const int tid = threadIdx.x, w = tid >> 6, l = tid & 63;
  const int wr = w >> 2, wc = w & 3, lr = l & 15, lk = l >> 4;

  const int arow = tid >> 3;       // 64 rows, 8 thr/row
  const int acol = (tid & 7) * 8;  // 8 floats per thread
  const float* Ax = x + (size_t)(bm + arow) * DD + acol;
  const ushort* Bg = WcatT + (size_t)bn * DD;

  float4 ra[2];
  f32x4 z = {0.f, 0.f, 0.f, 0.f};
  f32x4 acc[2][2];
#pragma unroll
  for (int m = 0; m < 2; ++m)
#pragma unroll
    for (int n = 0; n < 2; ++n) acc[m][n] = z;

#define LOADA(t)                                                 \
  {                                                              \
    const float4* p = (const float4*)(Ax + (((t) & 15) << 6));   \
    ra[0] = p[0];                                                \
    ra[1] = p[1];                                                \
  }
#define WRITEA(lds) \
  { *(bf16x8*)((lds) + swz128(arow, acol * 2)) = pack8(ra[0], ra[1]); }

  LOADA(0);
  stage_swz128<2, 512>(Bg, DD, 0, sm + 8192, tid);
  asm volatile("s_waitcnt vmcnt(2)" ::: "memory");  // A(0) regs ready
  WRITEA(sm);
  LOADA(1);

  int cur = 0;
  for (int t = 0; t < 16; ++t) {
    char* nxt = sm + (cur ^ 1) * 24576;
    stage_swz128<2, 512>(Bg, DD, ((t + 1) & 15) << 6, nxt + 8192, tid);
    asm volatile("s_waitcnt vmcnt(2)" ::: "memory");  // B(t)+A(t+1) done
    WRITEA(nxt);
    LOADA(t + 2);  // wrapped, harmless
    asm volatile("s_waitcnt lgkmcnt(0)" ::: "memory");
    __builtin_amdgcn_s_barrier();
    const char* cp = sm + cur * 24576;
#pragma unroll
    for (int ks = 0; ks < 2; ++ks) {
      const int kb = ks * 64 + lk * 16;
      bf16x8 af[2], bfp[2];
#pragma unroll
      for (int m = 0; m < 2; ++m)
        af[m] = ld_swz128(cp, wr * 32 + m * 16 + lr, kb);
#pragma unroll
      for (int n = 0; n < 2; ++n)
        bfp[n] = ld_swz128(cp + 8192, wc * 32 + n * 16 + lr, kb);
#pragma unroll
      for (int m = 0; m < 2; ++m)
#pragma unroll
        for (int n = 0; n < 2; ++n)
          acc[m][n] = __builtin_amdgcn_mfma_f32_16x16x32_bf16(af[m], bfp[n], acc[m][n], 0, 0, 0);
    }
    __builtin_amdgcn_s_barrier();
    cur ^= 1;
  }
  asm volatile("s_waitcnt vmcnt(0)" ::: "memory");
  __syncthreads();  // other waves' wrapped gll16 prefetches must land before LDS reuse
#undef LOADA
#undef WRITEA

  if (bn == 0) {
    // ---- XP tile (bm..bm+63, all 128 feats) -> swizzled LDS ----
#pragma unroll
    for (int m = 0; m < 2; ++m)
#pragma unroll
      for (int n = 0; n < 2; ++n) {
        const int rowl = wr * 32 + m * 16 + lk * 4;
        const int col = wc * 32 + n * 16 + lr;
        const float bv = bcat[col];
#pragma unroll
        for (int j = 0; j < 4; ++j)
          *(ushort*)(sm + swzoff(rowl + j, col * 2)) = f2bf(acc[m][n][j] + bv);
      }
    // ---- stage QKcT[256][128] (64 KB, L2-resident) ----
    stage_swz<8, 512>(QKcT, PP, 0, sm + 16384, tid);
    __syncthreads();  // waits lgkm (XP writes) + vm (gll16)

    // ---- QK GEMM: M=64, N=256, K=128; warp grid 2x4 ----
    f32x4 a2[2][4];
#pragma unroll
    for (int m = 0; m < 2; ++m)
#pragma unroll
      for (int n = 0; n < 4; ++n) a2[m][n] = z;
#pragma unroll
    for (int ks = 0; ks < 4; ++ks) {
      const int kb = ks * 64 + lk * 16;
      bf16x8 af[2], bfp[4];
#pragma unroll
      for (int m = 0; m < 2; ++m)
        af[m] = ld_swz(sm, wr * 32 + m * 16 + lr, kb);
#pragma unroll
      for (int n = 0; n < 4; ++n)
        bfp[n] = ld_swz(sm + 16384, wc * 64 + n * 16 + lr, kb);
#pragma unroll
      for (int m = 0; m < 2; ++m)
#pragma unroll
        for (int n = 0; n < 4; ++n)
          a2[m][n] = __builtin_amdgcn_mfma_f32_16x16x32_bf16(af[m], bfp[n], a2[m][n], 0, 0, 0);
    }
    __syncthreads();  // XP reads done; sm reusable for Kd tile

    // ---- Q -> Qb; Kd = K*decay -> swizzled LDS [feat][time] at sm+16K ----
#pragma unroll
    for (int m = 0; m < 2; ++m)
#pragma unroll
      for (int n = 0; n < 4; ++n) {
        const int rowl = wr * 32 + m * 16 + lk * 4;
        const int col = wc * 64 + n * 16 + lr;
        if (col < 128) {
#pragma unroll
          for (int j = 0; j < 4; ++j)
            Qb[(size_t)(bm + rowl + j) * PP + col] = f2bf(a2[m][n][j]);
        } else {
          const int cc = col - 128;
#pragma unroll
          for (int j = 0; j < 4; ++j) {
            float v = a2[m][n][j] * decay[(bm + rowl + j) & (TT - 1)];
            *(ushort*)(sm + 16384 + swz128(cc, (rowl + j) * 2)) = f2bf(v);
          }
        }
      }
    __syncthreads();  // Kd tile complete

    // ---- KdT dump: 128 feats x 64 times, coalesced 16B/lane ----
    {
      const int cc = tid >> 2;
#pragma unroll
      for (int i = 0; i < 2; ++i) {
        const int ch = (tid & 3) * 2 + i;
        bf16x8 v = ld_swz128(sm + 16384, cc, ch * 16);
        *(bf16x8*)&KdT[(size_t)cc * (BB * TT) + bm + ch * 8] = v;
      }
    }
  } else {
    ushort(*VTt)[72] = (ushort(*)[72]) & sm[0];  // 128x72 ushort = 18KB
#pragma unroll
    for (int m = 0; m < 2; ++m)
#pragma unroll
      for (int n = 0; n < 2; ++n) {
        const int tl = wr * 32 + m * 16 + lk * 4;  // local time 0..63
        const int cc = wc * 32 + n * 16 + lr;      // feature 0..127
        const float bv = bcat[128 + cc];
#pragma unroll
        for (int j = 0; j < 4; ++j) {
          ushort u = f2bf(acc[m][n][j] + bv);
          V[(size_t)(bm + tl + j) * PP + cc] = u;
          VTt[cc][tl + j] = u;
        }
      }
    __syncthreads();
    const int row = tid >> 2;  // feature 0..127
#pragma unroll
    for (int i = 0; i < 2; ++i) {
      const int ch = (tid & 3) * 2 + i;  // 8-time chunk 0..7
      bf16x8 v = *(const bf16x8*)&VTt[row][ch * 8];
      *(bf16x8*)&VT[(size_t)row * (BB * TT) + bm + ch * 8] = v;
    }
  }
}

// ---------------------------------------------------------------------------
// Chunk state S[bc][j][i] = sum_s Kd[s][j]*V[s][i], global-direct MFMA.
// grid 256: (chunk, quadrant qj x qi), XCD swizzle. Output bf16 (Scb).
// ---------------------------------------------------------------------------
__global__ __launch_bounds__(256) void chunk_state(
    const ushort* __restrict__ KdT, const ushort* __restrict__ VT,
    ushort* __restrict__ Scb) {
  const int p = blockIdx.x;
  const int xcd = p & 7, idx = p >> 3;
  const int bc = xcd + 8 * (idx >> 2);  // 0..63
  const int q = idx & 3;
  const int qj = q >> 1, qi = q & 1;
  const size_t r0 = (size_t)(bc >> 4) * TT + (bc & 15) * CH;
  const int tid = threadIdx.x, w = tid >> 6, l = tid & 63;
  const int wr = w >> 1, wc = w & 1, lr = l & 15, lk = l >> 4;

  f32x4 z = {0.f, 0.f, 0.f, 0.f};
  f32x4 acc[2][2];
#pragma unroll
  for (int m = 0; m < 2; ++m)
#pragma unroll
    for (int n = 0; n < 2; ++n) acc[m][n] = z;
#pragma unroll
  for (int ks = 0; ks < 4; ++ks) {
    const int kk = ks * 32 + lk * 8;
    bf16x8 af[2], bf[2];
#pragma unroll
    for (int m = 0; m < 2; ++m)
      af[m] = *(const bf16x8*)&KdT[(size_t)(qj * 64 + wr * 32 + m * 16 + lr) * (BB * TT) + r0 + kk];
#pragma unroll
    for (int n = 0; n < 2; ++n)
      bf[n] = *(const bf16x8*)&VT[(size_t)(qi * 64 + wc * 32 + n * 16 + lr) * (BB * TT) + r0 + kk];
#pragma unroll
    for (int m = 0; m < 2; ++m)
#pragma unroll
      for (int n = 0; n < 2; ++n)
        acc[m][n] = __builtin_amdgcn_mfma_f32_16x16x32_bf16(af[m], bf[n], acc[m][n], 0, 0, 0);
  }
#pragma unroll
  for (int m = 0; m < 2; ++m)
#pragma unroll
    for (int n = 0; n < 2; ++n)
#pragma unroll
      for (int j = 0; j < 4; ++j)
        Scb[(size_t)bc * 16384 +
            (size_t)(qj * 64 + wr * 32 + m * 16 + lk * 4 + j) * 128 +
            (qi * 64 + wc * 32 + n * 16 + lr)] = f2bf(acc[m][n][j]);
}

// ---------------------------------------------------------------------------
// Exclusive prefix over chunks (bf16 partials, fp32 accumulate) -> SxT bf16
// ---------------------------------------------------------------------------
__global__ __launch_bounds__(256) void chunk_scan(const ushort* __restrict__ Scb,
                                                  ushort* __restrict__ SxT) {
  const int b = blockIdx.y;
  const int e = blockIdx.x * 256 + threadIdx.x;
  float run = 0.f;
#pragma unroll
  for (int c = 0; c < NC; ++c) {
    const size_t idx = (size_t)(b * NC + c) * 16384 + e;
    SxT[idx] = f2bf(run);
    run += bf2f(Scb[idx]);
  }
}

// ---------------------------------------------------------------------------
// Attention core, 4 blocks per (b,c): (hr, hc). grid 256, XCD co-located.
// Y = tril(Q V^T) Kd + Q Sx   (decay folded into Kd and Sx)
// Causal trim: hr=0 rows only see s<64 -> skip score cols 64-127 and the
// upper half of the Am@Kd K-range (block-uniform branches).
// ---------------------------------------------------------------------------
__global__ __launch_bounds__(256) void attn_mfma(
    const ushort* __restrict__ Qb, const ushort* __restrict__ V,
    const ushort* __restrict__ KdT, const ushort* __restrict__ SxT,
    ushort* __restrict__ Y) {
  __shared__ char Am[64 * 256];  // 16 KB swizzled scores, local rows
  const int p = blockIdx.x;
  const int xcd = p & 7, idx = p >> 3;
  const int bc = xcd + 8 * (idx >> 2);
  const int q = idx & 3;
  const int hr = q >> 1, hc = q & 1;
  const size_t r0 = (size_t)(bc >> 4) * TT + (bc & 15) * CH;
  const int tid = threadIdx.x, w = tid >> 6, l = tid & 63;
  const int wr = w >> 1, wc = w & 1, lr = l & 15, lk = l >> 4;

  f32x4 z = {0.f, 0.f, 0.f, 0.f};

  // phase 1: raw scores A[t][s] = Q[t]·V[s], rows hr*64 + wr*32 + m*16.
  // hr==0: only cols 0..63 are unmasked -> wc==1 waves skip entirely.
  if (hr == 1 || wc == 0) {
    f32x4 a1[2][4];
#pragma unroll
    for (int m = 0; m < 2; ++m)
#pragma unroll
      for (int n = 0; n < 4; ++n) a1[m][n] = z;
#pragma unroll
    for (int ks = 0; ks < 4; ++ks) {
      const int kk = ks * 32 + lk * 8;
      bf16x8 af[2], bf[4];
#pragma unroll
      for (int m = 0; m < 2; ++m)
        af[m] = *(const bf16x8*)&Qb[(r0 + hr * 64 + wr * 32 + m * 16 + lr) * 128 + kk];
#pragma unroll
      for (int n = 0; n < 4; ++n)
        bf[n] = *(const bf16x8*)&V[(r0 + wc * 64 + n * 16 + lr) * 128 + kk];
#pragma unroll
      for (int m = 0; m < 2; ++m)
#pragma unroll
        for (int n = 0; n < 4; ++n)
          a1[m][n] = __builtin_amdgcn_mfma_f32_16x16x32_bf16(af[m], bf[n], a1[m][n], 0, 0, 0);
    }
#pragma unroll
    for (int m = 0; m < 2; ++m)
#pragma unroll
      for (int n = 0; n < 4; ++n)
#pragma unroll
        for (int j = 0; j < 4; ++j) {
          int tl = wr * 32 + m * 16 + lk * 4 + j;  // local row
          int t = hr * 64 + tl;
          int s = wc * 64 + n * 16 + lr;
          float v = (s <= t) ? a1[m][n][j] : 0.f;
          *(ushort*)(Am + swzoff(tl, s * 2)) = f2bf(v);
        }
  }
  __syncthreads();

  // phase 2: Y[64x64] = Am @ Kd + Q @ Sx ; warp grid 2x2, wave 32x32
  f32x4 a2[2][2];
#pragma unroll
  for (int m = 0; m < 2; ++m)
#pragma unroll
    for (int n = 0; n < 2; ++n) a2[m][n] = z;
  // Am @ Kd: hr==0 only needs s<64 (ks 0..1)
  const int nks = hr ? 4 : 2;
  for (int ks = 0; ks < nks; ++ks) {
    const int kb = ks * 64 + lk * 16, kk = ks * 32 + lk * 8;
    bf16x8 af[2], bf[2];
#pragma unroll
    for (int m = 0; m < 2; ++m)
      af[m] = ld_swz(Am, wr * 32 + m * 16 + lr, kb);
#pragma unroll
    for (int n = 0; n < 2; ++n)
      bf[n] = *(const bf16x8*)&KdT[(size_t)(hc * 64 + wc * 32 + n * 16 + lr) * (BB * TT) + r0 + kk];
#pragma unroll
    for (int m = 0; m < 2; ++m)
#pragma unroll
      for (int n = 0; n < 2; ++n)
        a2[m][n] = __builtin_amdgcn_mfma_f32_16x16x32_bf16(af[m], bf[n], a2[m][n], 0, 0, 0);
  }
#pragma unroll
  for (int ks = 0; ks < 4; ++ks) {
    const int kk = ks * 32 + lk * 8;
    bf16x8 af[2], bf[2];
#pragma unroll
    for (int m = 0; m < 2; ++m)
      af[m] = *(const bf16x8*)&Qb[(r0 + hr * 64 + wr * 32 + m * 16 + lr) * 128 + kk];
#pragma unroll
    for (int n = 0; n < 2; ++n)
      bf[n] = *(const bf16x8*)&SxT[(size_t)bc * 16384 +
                                   (size_t)(hc * 64 + wc * 32 + n * 16 + lr) * 128 + kk];
#pragma unroll
    for (int m = 0; m < 2; ++m)
#pragma unroll
      for (int n = 0; n < 2; ++n)
        a2[m][n] = __builtin_amdgcn_mfma_f32_16x16x32_bf16(af[m], bf[n], a2[m][n], 0, 0, 0);
  }
#pragma unroll
  for (int m = 0; m < 2; ++m)
#pragma unroll
    for (int n = 0; n < 2; ++n)
#pragma unroll
      for (int j = 0; j < 4; ++j) {
        int t = hr * 64 + wr * 32 + m * 16 + lk * 4 + j;
        int col = hc * 64 + wc * 32 + n * 16 + lr;
        Y[(r0 + t) * 128 + col] = f2bf(a2[m][n][j]);
      }
}

// ---------------------------------------------------------------------------
// GEMM3: Y[8192x128] @ W_o + b_o -> out fp32. Single-shot K=128. grid 1024.
// ---------------------------------------------------------------------------
__global__ __launch_bounds__(256) void gemm_out(
    const ushort* __restrict__ Y, const ushort* __restrict__ WoT,
    const float* __restrict__ b_o, float* __restrict__ out) {
  __shared__ char sm[49152];  // A 16K | B 32K
  const int bid = blockIdx.x;
  const int swz = (bid & 7) * 128 + (bid >> 3);
  const int bm = (swz >> 3) * 64, bn = (swz & 7) * 128;
  const int tid = threadIdx.x, w = tid >> 6, l = tid & 63;
  const int wr = w >> 1, wc = w & 1, lr = l & 15, lk = l >> 4;
  stage_swz<4, 256>(Y + (size_t)bm * PP, PP, 0, sm, tid);
  stage_swz<8, 256>(WoT + (size_t)bn * PP, PP, 0, sm + 16384, tid);
  f32x4 z = {0.f, 0.f, 0.f, 0.f};
  f32x4 acc[2][4];
#pragma unroll
  for (int m = 0; m < 2; ++m)
#pragma unroll
    for (int n = 0; n < 4; ++n) acc[m][n] = z;
  __syncthreads();
#pragma unroll
  for (int ks = 0; ks < 4; ++ks) {
    const int kb = ks * 64 + lk * 16;
    bf16x8 af[2], bfp[4];
#pragma unroll
    for (int m = 0; m < 2; ++m) af[m] = ld_swz(sm, wr * 32 + m * 16 + lr, kb);
#pragma unroll
    for (int n = 0; n < 4; ++n)
      bfp[n] = ld_swz(sm + 16384, wc * 64 + n * 16 + lr, kb);
#pragma unroll
    for (int m = 0; m < 2; ++m)
#pragma unroll
      for (int n = 0; n < 4; ++n)
        acc[m][n] = __builtin_amdgcn_mfma_f32_16x16x32_bf16(af[m], bfp[n], acc[m][n], 0, 0, 0);
  }
#pragma unroll
  for (int m = 0; m < 2; ++m)
#pragma unroll
    for (int n = 0; n < 4; ++n) {
      const int rowb = bm + wr * 32 + m * 16 + lk * 4;
      const int col = bn + wc * 64 + n * 16 + lr;
      const float bv = b_o[col];
#pragma unroll
      for (int j = 0; j < 4; ++j)
        out[(size_t)(rowb + j) * DD + col] = acc[m][n][j] + bv;
    }
}

// ---------------------------------------------------------------------------
extern "C" void kernel_launch(void* const* d_in, const int* in_sizes, int n_in,
                              void* d_out, int out_size, void* d_ws, size_t ws_size,
                              hipStream_t stream) {
  const float* x = (const float*)d_in[0];
  const float* Qf = (const float*)d_in[1];
  const float* Kf = (const float*)d_in[2];
  const float* W_in = (const float*)d_in[3];
  const float* b_in = (const float*)d_in[4];
  const float* W_v = (const float*)d_in[5];
  const float* b_v = (const float*)d_in[6];
  const float* W_o = (const float*)d_in[7];
  const float* b_o = (const float*)d_in[8];
  const float* decay = (const float*)d_in[9];
  float* out = (float*)d_out;
  char* W = (char*)d_ws;

  ushort* V     = (ushort*)(W);                  // 2 MB
  ushort* VT    = (ushort*)(W + 2097152);        // 2 MB
  ushort* Qb    = (ushort*)(W + 4194304);        // 2 MB
  ushort* KdT   = (ushort*)(W + 6291456);        // 2 MB
  ushort* Scb   = (ushort*)(W + 8388608);        // 2 MB (bf16 partial states)
  ushort* SxT   = (ushort*)(W + 10485760);       // 2 MB
  ushort* Yb    = (ushort*)(W + 12582912);       // 2 MB
  ushort* WcatT = (ushort*)(W + 14680064);       // 512 KB
  ushort* QKcT  = (ushort*)(W + 15204352);       // 64 KB
  ushort* WoT   = (ushort*)(W + 15269888);       // 256 KB
  float*  bcat  = (float*)(W + 15532032);        // 1 KB

  prep_t<<<105, 256, 0, stream>>>(Qf, Kf, W_in, b_in, W_v, b_v, W_o,
                                  WcatT, QKcT, WoT, bcat);
  gemm_xw<<<256, 512, 0, stream>>>(x, WcatT, QKcT, bcat, decay,
                                   Qb, KdT, V, VT);
  chunk_state<<<256, 256, 0, stream>>>(KdT, VT, Scb);
  chunk_scan<<<dim3(64, BB), 256, 0, stream>>>(Scb, SxT);
  attn_mfma<<<256, 256, 0, stream>>>(Qb, V, KdT, SxT, Yb);
  gemm_out<<<1024, 256, 0, stream>>>(Yb, WoT, b_o, out);
}